// Round 11
// baseline (319.328 us; speedup 1.0000x reference)
//
#include <hip/hip_runtime.h>
#include <stdint.h>

#define D_IN  128
#define D_OUT 64
#define BN_EPS 1e-3f

#define BIN_SHIFT 6
#define BIN_NODES 64           // 1 << BIN_SHIFT
#define BIN_CAP   2560         // avg 2048 records/bin, +11 sigma headroom
#define CHUNK     4096         // edges per partition block (782 blocks, 3/CU)
#define MAX_BINS  1600

typedef __attribute__((ext_vector_type(8))) short bf16x8;
typedef __attribute__((ext_vector_type(4))) float f32x4;

__device__ __forceinline__ ushort f32_to_bf16_rne(float f) {
  uint u = __float_as_uint(f);
  u += 0x7FFFu + ((u >> 16) & 1u);
  return (ushort)(u >> 16);
}
__device__ __forceinline__ float bf16_to_f32(ushort h) {
  return __uint_as_float((uint)h << 16);
}

// ------------- GEMM via MFMA: pre16 = bf16(X @ W), bf16 in / fp32 acc -------
__global__ __launch_bounds__(256) void gemm_mfma_kernel(
    const float* __restrict__ x, const float* __restrict__ W,
    ushort* __restrict__ pre16, int n_nodes, int n_tiles) {
  __shared__ ushort Wb[D_IN * D_OUT];  // 16 KB bf16 copy of W
  const int t = threadIdx.x;
  for (int i = t; i < D_IN * D_OUT; i += 256) Wb[i] = f32_to_bf16_rne(W[i]);
  __syncthreads();

  const int lane = t & 63;
  const int wave = t >> 6;
  const int m = lane & 15;
  const int quad = lane >> 4;

  bf16x8 bfrag[4][4];
#pragma unroll
  for (int nt = 0; nt < 4; ++nt)
#pragma unroll
    for (int s = 0; s < 4; ++s)
#pragma unroll
      for (int j = 0; j < 8; ++j)
        bfrag[nt][s][j] =
            (short)Wb[(32 * s + quad * 8 + j) * D_OUT + nt * 16 + m];

  for (int tile = blockIdx.x; tile < n_tiles; tile += gridDim.x) {
    const int rbase = tile * 64 + wave * 16;
    const int row = rbase + m;
    const size_t rl = (size_t)min(row, n_nodes - 1);
    f32x4 acc0 = {0.f, 0.f, 0.f, 0.f}, acc1 = {0.f, 0.f, 0.f, 0.f};
    f32x4 acc2 = {0.f, 0.f, 0.f, 0.f}, acc3 = {0.f, 0.f, 0.f, 0.f};
#pragma unroll
    for (int s = 0; s < 4; ++s) {
      const float4 xa = *(const float4*)&x[rl * D_IN + s * 32 + quad * 8];
      const float4 xb = *(const float4*)&x[rl * D_IN + s * 32 + quad * 8 + 4];
      bf16x8 af;
      af[0] = (short)f32_to_bf16_rne(xa.x);
      af[1] = (short)f32_to_bf16_rne(xa.y);
      af[2] = (short)f32_to_bf16_rne(xa.z);
      af[3] = (short)f32_to_bf16_rne(xa.w);
      af[4] = (short)f32_to_bf16_rne(xb.x);
      af[5] = (short)f32_to_bf16_rne(xb.y);
      af[6] = (short)f32_to_bf16_rne(xb.z);
      af[7] = (short)f32_to_bf16_rne(xb.w);
      acc0 = __builtin_amdgcn_mfma_f32_16x16x32_bf16(af, bfrag[0][s], acc0, 0, 0, 0);
      acc1 = __builtin_amdgcn_mfma_f32_16x16x32_bf16(af, bfrag[1][s], acc1, 0, 0, 0);
      acc2 = __builtin_amdgcn_mfma_f32_16x16x32_bf16(af, bfrag[2][s], acc2, 0, 0, 0);
      acc3 = __builtin_amdgcn_mfma_f32_16x16x32_bf16(af, bfrag[3][s], acc3, 0, 0, 0);
    }
#pragma unroll
    for (int reg = 0; reg < 4; ++reg) {
      const int r = rbase + quad * 4 + reg;
      if (r < n_nodes) {
        ushort* po = &pre16[(size_t)r * D_OUT + m];
        po[0]  = f32_to_bf16_rne(acc0[reg]);
        po[16] = f32_to_bf16_rne(acc1[reg]);
        po[32] = f32_to_bf16_rne(acc2[reg]);
        po[48] = f32_to_bf16_rne(acc3[reg]);
      }
    }
  }
}

// ---------------- Partition: bin edges by dst>>6, x4-vectorized loads ---------
// record: w0 = (dst_low6 << 17) | src17 ; w1 = fp32 edge_val
__global__ __launch_bounds__(256) void partition_kernel(
    const float* __restrict__ ev, const int* __restrict__ esrc,
    const int* __restrict__ edst, int* __restrict__ bin_cursor,
    uint2* __restrict__ bucket, int n_edges, int n_bins) {
  __shared__ int cnt[MAX_BINS];
  __shared__ int base[MAX_BINS];
  const int t = threadIdx.x;
  const int beg = blockIdx.x * CHUNK;
  const int end = min(beg + CHUNK, n_edges);

  for (int i = t; i < n_bins; i += 256) cnt[i] = 0;
  __syncthreads();

  // phase A: histogram, 4 edges per lane per load (1 KB/wave coalesced)
  for (int i = beg + t * 4; i < end; i += 1024) {
    if (i + 3 < end) {
      const int4 d4 = *(const int4*)&edst[i];
      atomicAdd(&cnt[d4.x >> BIN_SHIFT], 1);
      atomicAdd(&cnt[d4.y >> BIN_SHIFT], 1);
      atomicAdd(&cnt[d4.z >> BIN_SHIFT], 1);
      atomicAdd(&cnt[d4.w >> BIN_SHIFT], 1);
    } else {
      for (int k = i; k < end; ++k) atomicAdd(&cnt[edst[k] >> BIN_SHIFT], 1);
    }
  }
  __syncthreads();

  // phase B: reserve contiguous space per (block, bin)
  for (int i = t; i < n_bins; i += 256) {
    const int c = cnt[i];
    int b = 0;
    if (c > 0) b = atomicAdd(&bin_cursor[i], c);
    if (b > BIN_CAP) b = BIN_CAP;
    base[i] = i * BIN_CAP + b;
    cnt[i] = 0;  // reuse as rank cursor
  }
  __syncthreads();

  // phase C: scatter records (re-reads are L2-hot from phase A)
  for (int i = beg + t * 4; i < end; i += 1024) {
    if (i + 3 < end) {
      const int4 d4 = *(const int4*)&edst[i];
      const int4 s4 = *(const int4*)&esrc[i];
      const float4 v4 = *(const float4*)&ev[i];
#pragma unroll
      for (int k = 0; k < 4; ++k) {
        const int dst = (&d4.x)[k];
        const int src = (&s4.x)[k];
        const float v = (&v4.x)[k];
        const int bin = dst >> BIN_SHIFT;
        const int r = atomicAdd(&cnt[bin], 1);
        const int pos = base[bin] + r;
        if (pos < (bin + 1) * BIN_CAP) {
          const uint w0 = ((uint)(dst & (BIN_NODES - 1)) << 17) | (uint)src;
          bucket[pos] = make_uint2(w0, __float_as_uint(v));
        }
      }
    } else {
      for (int k = i; k < end; ++k) {
        const int dst = edst[k];
        const int bin = dst >> BIN_SHIFT;
        const int r = atomicAdd(&cnt[bin], 1);
        const int pos = base[bin] + r;
        if (pos < (bin + 1) * BIN_CAP) {
          const uint w0 = ((uint)(dst & (BIN_NODES - 1)) << 17) | (uint)esrc[k];
          bucket[pos] = make_uint2(w0, __float_as_uint(ev[k]));
        }
      }
    }
  }
}

// ------- Bin sort+gather: LDS counting sort, quarter-wave gather (uint2) ------
__global__ __launch_bounds__(256) void bin_sort_gather_kernel(
    const ushort* __restrict__ pre16, const uint2* __restrict__ bucket,
    const int* __restrict__ bin_cursor, float* __restrict__ out,
    float* __restrict__ stats, int n_nodes) {
  __shared__ uint s_src[BIN_CAP];          // 10.0 KB
  __shared__ ushort s_val[BIN_CAP];        // 5.0 KB
  __shared__ int s_hist[BIN_NODES];
  __shared__ int s_off[BIN_NODES + 1];
  __shared__ int s_cur[BIN_NODES];

  const int t = threadIdx.x;
  const int bin = blockIdx.x;
  const int cnt = min(bin_cursor[bin], BIN_CAP);
  const int64_t rbase = (int64_t)bin * BIN_CAP;

  if (t < BIN_NODES) s_hist[t] = 0;
  __syncthreads();

  for (int i = t; i < cnt; i += 256)
    atomicAdd(&s_hist[bucket[rbase + i].x >> 17], 1);
  __syncthreads();

  int own = (t < BIN_NODES) ? s_hist[t] : 0;
  for (int off = 1; off < BIN_NODES; off <<= 1) {
    int u = 0;
    if (t < BIN_NODES && t >= off) u = s_hist[t - off];
    __syncthreads();
    if (t < BIN_NODES) s_hist[t] += u;
    __syncthreads();
  }
  if (t < BIN_NODES) {
    const int e = s_hist[t] - own;
    s_off[t] = e;
    s_cur[t] = e;
  }
  if (t == 0) s_off[BIN_NODES] = cnt;
  __syncthreads();

  for (int i = t; i < cnt; i += 256) {
    const uint2 r = bucket[rbase + i];
    const int d = r.x >> 17;
    const int p = atomicAdd(&s_cur[d], 1);
    s_src[p] = r.x & 0x1FFFFu;
    s_val[p] = f32_to_bf16_rne(__uint_as_float(r.y));
  }
  __syncthreads();

  // gather: wave per node; quarter-waves (16 lanes x 4 cols) per record stream;
  // 4 quarters x 4-unroll = 16 records in flight per wave
  const int lane = t & 63;
  const int wave = t >> 6;
  const int q = lane >> 4;      // quarter id: record stream j = jb + q, step 4
  const int ql = lane & 15;     // col group: cols 4*ql .. 4*ql+3
  const int node0 = bin * BIN_NODES;
  float cs[4] = {}, cs2[4] = {};

  for (int nl = wave; nl < BIN_NODES; nl += 4) {
    const int node = node0 + nl;
    if (node < n_nodes) {
      const int jb = s_off[nl], je = s_off[nl + 1];
      float a0[4] = {}, a1[4] = {}, a2[4] = {}, a3[4] = {};
      int j = jb + q;
      for (; j + 12 < je; j += 16) {
        const uint src0 = s_src[j];
        const uint src1 = s_src[j + 4];
        const uint src2 = s_src[j + 8];
        const uint src3 = s_src[j + 12];
        const float v0 = bf16_to_f32(s_val[j]);
        const float v1 = bf16_to_f32(s_val[j + 4]);
        const float v2 = bf16_to_f32(s_val[j + 8]);
        const float v3 = bf16_to_f32(s_val[j + 12]);
        const uint2 p0 = *(const uint2*)&pre16[(size_t)src0 * D_OUT + 4 * ql];
        const uint2 p1 = *(const uint2*)&pre16[(size_t)src1 * D_OUT + 4 * ql];
        const uint2 p2 = *(const uint2*)&pre16[(size_t)src2 * D_OUT + 4 * ql];
        const uint2 p3 = *(const uint2*)&pre16[(size_t)src3 * D_OUT + 4 * ql];
        a0[0] += v0 * bf16_to_f32((ushort)(p0.x & 0xFFFFu));
        a0[1] += v0 * bf16_to_f32((ushort)(p0.x >> 16));
        a0[2] += v0 * bf16_to_f32((ushort)(p0.y & 0xFFFFu));
        a0[3] += v0 * bf16_to_f32((ushort)(p0.y >> 16));
        a1[0] += v1 * bf16_to_f32((ushort)(p1.x & 0xFFFFu));
        a1[1] += v1 * bf16_to_f32((ushort)(p1.x >> 16));
        a1[2] += v1 * bf16_to_f32((ushort)(p1.y & 0xFFFFu));
        a1[3] += v1 * bf16_to_f32((ushort)(p1.y >> 16));
        a2[0] += v2 * bf16_to_f32((ushort)(p2.x & 0xFFFFu));
        a2[1] += v2 * bf16_to_f32((ushort)(p2.x >> 16));
        a2[2] += v2 * bf16_to_f32((ushort)(p2.y & 0xFFFFu));
        a2[3] += v2 * bf16_to_f32((ushort)(p2.y >> 16));
        a3[0] += v3 * bf16_to_f32((ushort)(p3.x & 0xFFFFu));
        a3[1] += v3 * bf16_to_f32((ushort)(p3.x >> 16));
        a3[2] += v3 * bf16_to_f32((ushort)(p3.y & 0xFFFFu));
        a3[3] += v3 * bf16_to_f32((ushort)(p3.y >> 16));
      }
      for (; j < je; j += 4) {
        const uint src = s_src[j];
        const float v = bf16_to_f32(s_val[j]);
        const uint2 p = *(const uint2*)&pre16[(size_t)src * D_OUT + 4 * ql];
        a0[0] += v * bf16_to_f32((ushort)(p.x & 0xFFFFu));
        a0[1] += v * bf16_to_f32((ushort)(p.x >> 16));
        a0[2] += v * bf16_to_f32((ushort)(p.y & 0xFFFFu));
        a0[3] += v * bf16_to_f32((ushort)(p.y >> 16));
      }
      float r[4];
#pragma unroll
      for (int k = 0; k < 4; ++k) {
        float vsum = (a0[k] + a1[k]) + (a2[k] + a3[k]);
        vsum += __shfl_xor(vsum, 16);   // merge quarters 0<->1, 2<->3
        vsum += __shfl_xor(vsum, 32);   // merge halves
        r[k] = vsum;
      }
      if (q == 0) {
        *(float4*)&out[(size_t)node * D_OUT + 4 * ql] =
            make_float4(r[0], r[1], r[2], r[3]);
#pragma unroll
        for (int k = 0; k < 4; ++k) {
          cs[k] += r[k];
          cs2[k] += r[k] * r[k];
        }
      }
    }
  }
  __syncthreads();  // record reads done; alias reduction buffers onto s_src

  float* red = (float*)s_src;       // [4 waves][64 cols] sums
  float* red2 = red + 256;          // [4 waves][64 cols] sumsq
  if (q == 0) {
#pragma unroll
    for (int k = 0; k < 4; ++k) {
      red[wave * 64 + 4 * ql + k] = cs[k];
      red2[wave * 64 + 4 * ql + k] = cs2[k];
    }
  }
  __syncthreads();
  if (t < 64) {
    float s = red[t] + red[64 + t] + red[128 + t] + red[192 + t];
    float s2 = red2[t] + red2[64 + t] + red2[128 + t] + red2[192 + t];
    atomicAdd(&stats[t], s);
    atomicAdd(&stats[64 + t], s2);
  }
}

// ---------------- Normalize + ReLU (in place, float4) ----------------
__global__ __launch_bounds__(256) void norm_kernel(
    float* __restrict__ out, const float* __restrict__ stats, int64_t n_vec4,
    float inv_n) {
  const int c = (threadIdx.x * 4) & 63;
  float mean[4], scale[4];
#pragma unroll
  for (int k = 0; k < 4; ++k) {
    mean[k] = stats[c + k] * inv_n;
    const float var = stats[64 + c + k] * inv_n - mean[k] * mean[k];
    scale[k] = rsqrtf(var + BN_EPS);
  }
  const int64_t stride = (int64_t)gridDim.x * 256;
  for (int64_t i = (int64_t)blockIdx.x * 256 + threadIdx.x; i < n_vec4;
       i += stride) {
    float4 v = ((float4*)out)[i];
    v.x = (v.x - mean[0]) * scale[0];
    v.y = (v.y - mean[1]) * scale[1];
    v.z = (v.z - mean[2]) * scale[2];
    v.w = (v.w - mean[3]) * scale[3];
    v.x = v.x > 0.f ? v.x : 0.f;
    v.y = v.y > 0.f ? v.y : 0.f;
    v.z = v.z > 0.f ? v.z : 0.f;
    v.w = v.w > 0.f ? v.w : 0.f;
    ((float4*)out)[i] = v;
  }
}

// ---------------- launch ----------------
extern "C" void kernel_launch(void* const* d_in, const int* in_sizes, int n_in,
                              void* d_out, int out_size, void* d_ws,
                              size_t ws_size, hipStream_t stream) {
  const float* x = (const float*)d_in[0];
  const float* W = (const float*)d_in[1];
  const float* ev = (const float*)d_in[2];
  const int* esrc = (const int*)d_in[3];
  const int* edst = (const int*)d_in[4];

  const int n_nodes = in_sizes[0] / D_IN;
  const int n_edges = in_sizes[2];
  const int64_t n_out = (int64_t)n_nodes * D_OUT;
  const int n_bins = (n_nodes + BIN_NODES - 1) >> BIN_SHIFT;
  const int n_row_tiles = (n_nodes + 63) / 64;

  float* out = (float*)d_out;

  // workspace layout
  char* w = (char*)d_ws;
  ushort* pre16 = (ushort*)w;             w += (size_t)n_nodes * D_OUT * 2;
  int* bin_cursor = (int*)w;              w += (size_t)n_bins * 4;
  float* stats = (float*)w;               w += 128 * 4;
  w = (char*)(((uintptr_t)w + 7) & ~(uintptr_t)7);
  uint2* bucket = (uint2*)w;              // n_bins * BIN_CAP * 8 bytes (~32 MB)

  hipMemsetAsync(bin_cursor, 0, (size_t)n_bins * 4, stream);
  hipMemsetAsync(stats, 0, 128 * 4, stream);

  gemm_mfma_kernel<<<(n_row_tiles + 1) / 2, 256, 0, stream>>>(
      x, W, pre16, n_nodes, n_row_tiles);
  partition_kernel<<<(n_edges + CHUNK - 1) / CHUNK, 256, 0, stream>>>(
      ev, esrc, edst, bin_cursor, bucket, n_edges, n_bins);
  bin_sort_gather_kernel<<<n_bins, 256, 0, stream>>>(pre16, bucket, bin_cursor,
                                                     out, stats, n_nodes);
  norm_kernel<<<2048, 256, 0, stream>>>(out, stats, n_out / 4,
                                        1.0f / (float)n_nodes);
}